// Round 1
// baseline (4003.472 us; speedup 1.0000x reference)
//
#include <hip/hip_runtime.h>

#define GD(x,y) (((x)+(y)-1)/(y))

// ---- softmax over alpha (tiny, 4 elements) ----
__global__ void softmax_k(const float* __restrict__ alpha, float* __restrict__ a, int n){
    if (threadIdx.x == 0 && blockIdx.x == 0){
        float m = alpha[0];
        for (int i = 1; i < n; ++i) m = fmaxf(m, alpha[i]);
        float s = 0.f;
        for (int i = 0; i < n; ++i){ float e = expf(alpha[i] - m); a[i] = e; s += e; }
        float inv = 1.f / s;
        for (int i = 0; i < n; ++i) a[i] *= inv;
    }
}

// ---- cur[n,:] = embedding[idx[n],:], float4 ----
__global__ void gather_k(const float* __restrict__ emb, const int* __restrict__ idx,
                         float* __restrict__ cur, int n_elem4, int d4){
    int i = blockIdx.x * blockDim.x + threadIdx.x;
    if (i >= n_elem4) return;
    int n = i / d4, d = i % d4;
    ((float4*)cur)[i] = ((const float4*)emb)[(size_t)idx[n] * d4 + d];
}

__global__ void zero_k(float4* __restrict__ p, int n4){
    int i = blockIdx.x * blockDim.x + threadIdx.x;
    if (i < n4) p[i] = make_float4(0.f, 0.f, 0.f, 0.f);
}

// ---- push-scatter SpMM: one wave per edge, lane handles float2 of 128 dims ----
__global__ void scatter_k(const int* __restrict__ row, const int* __restrict__ col,
                          const float* __restrict__ val, const float* __restrict__ cur,
                          float* __restrict__ nxt, int E){
    int t = blockIdx.x * blockDim.x + threadIdx.x;
    int e = t >> 6;
    if (e >= E) return;
    int lane = t & 63;
    int r = row[e], c = col[e];
    float v = val[e];
    const float2* s = (const float2*)(cur + (size_t)c * 128);
    float2 m = s[lane];
    float* d = nxt + (size_t)r * 128 + (size_t)lane * 2;
    atomicAdd(d,     v * m.x);
    atomicAdd(d + 1, v * m.y);
}

// ---- out[n,:] (+)= a[ai] * (src[n,:] @ W) (+ b on init); one wave per node ----
__global__ void proj_k(const float* __restrict__ src, const float* __restrict__ W,
                       const float* __restrict__ b, const float* __restrict__ a,
                       int ai, float* __restrict__ out, int N, int init){
    int t = blockIdx.x * blockDim.x + threadIdx.x;
    int n = t >> 6;
    if (n >= N) return;
    int lane = t & 63;
    const float* rowp = src + (size_t)n * 128;
    float x0 = rowp[lane], x1 = rowp[lane + 64];
    float s0 = x0 * W[lane * 2]     + x1 * W[(lane + 64) * 2];
    float s1 = x0 * W[lane * 2 + 1] + x1 * W[(lane + 64) * 2 + 1];
    for (int off = 32; off; off >>= 1){
        s0 += __shfl_down(s0, off);
        s1 += __shfl_down(s1, off);
    }
    if (lane == 0){
        float c = a[ai];
        float* o = out + (size_t)n * 2;
        if (init){ o[0] = b[0] + c * s0; o[1] = b[1] + c * s1; }
        else     { o[0] += c * s0;       o[1] += c * s1; }
    }
}

extern "C" void kernel_launch(void* const* d_in, const int* in_sizes, int n_in,
                              void* d_out, int out_size, void* d_ws, size_t ws_size,
                              hipStream_t stream) {
    const int*   node_idx = (const int*)  d_in[0];
    const int*   adj_row  = (const int*)  d_in[1];
    const int*   adj_col  = (const int*)  d_in[2];
    const float* adj_val  = (const float*)d_in[3];
    const float* emb      = (const float*)d_in[4];
    const float* alpha    = (const float*)d_in[5];
    const float* W        = (const float*)d_in[6];
    const float* b        = (const float*)d_in[7];
    float* out = (float*)d_out;

    const int N = in_sizes[0];      // 100000
    const int E = in_sizes[1];      // 1600000
    const int L = in_sizes[5] - 1;  // 3
    const int D = 128;

    float* cur = (float*)d_ws;
    float* nxt = cur + (size_t)N * D;
    float* a   = nxt + (size_t)N * D;

    softmax_k<<<1, 64, 0, stream>>>(alpha, a, L + 1);

    const int nd4 = N * D / 4;
    gather_k<<<GD(nd4, 256), 256, 0, stream>>>(emb, node_idx, cur, nd4, D / 4);

    proj_k<<<GD(N * 64, 256), 256, 0, stream>>>(cur, W, b, a, 0, out, N, 1);

    for (int i = 0; i < L; ++i){
        zero_k<<<GD(nd4, 256), 256, 0, stream>>>((float4*)nxt, nd4);
        scatter_k<<<GD(E * 64, 256), 256, 0, stream>>>(adj_row, adj_col, adj_val, cur, nxt, E);
        proj_k<<<GD(N * 64, 256), 256, 0, stream>>>(nxt, W, b, a, i + 1, out, N, 0);
        float* tmp = cur; cur = nxt; nxt = tmp;
    }
}

// Round 2
// 956.199 us; speedup vs baseline: 4.1869x; 4.1869x over previous
//
#include <hip/hip_runtime.h>

#define GD(x,y) (((x)+(y)-1)/(y))

// ---- softmax over alpha (tiny) ----
__global__ void softmax_k(const float* __restrict__ alpha, float* __restrict__ a, int n){
    if (threadIdx.x == 0 && blockIdx.x == 0){
        float m = alpha[0];
        for (int i = 1; i < n; ++i) m = fmaxf(m, alpha[i]);
        float s = 0.f;
        for (int i = 0; i < n; ++i){ float e = expf(alpha[i] - m); a[i] = e; s += e; }
        float inv = 1.f / s;
        for (int i = 0; i < n; ++i) a[i] *= inv;
    }
}

__global__ void zero_i(int* __restrict__ p, int n){
    int i = blockIdx.x * blockDim.x + threadIdx.x;
    if (i < n) p[i] = 0;
}

__global__ void hist_k(const int* __restrict__ row, int* __restrict__ deg, int E){
    int e = blockIdx.x * blockDim.x + threadIdx.x;
    if (e < E) atomicAdd(&deg[row[e]], 1);
}

// single-block exclusive scan of deg[N] -> row_ptr[N+1], cursor[N]
__global__ void scan_k(const int* __restrict__ deg, int* __restrict__ row_ptr,
                       int* __restrict__ cursor, int N, int E){
    __shared__ int lds[1024];
    int t = threadIdx.x;
    int C = GD(N, 1024);
    int beg = t * C, fin = min(beg + C, N);
    int s = 0;
    for (int i = beg; i < fin; ++i) s += deg[i];
    lds[t] = s; __syncthreads();
    // Hillis-Steele inclusive scan over 1024 thread sums
    for (int off = 1; off < 1024; off <<= 1){
        int add = (t >= off) ? lds[t - off] : 0;
        __syncthreads();
        lds[t] += add;
        __syncthreads();
    }
    int excl = lds[t] - s;
    int run = excl;
    for (int i = beg; i < fin; ++i){
        int d = deg[i];
        row_ptr[i] = run; cursor[i] = run;
        run += d;
    }
    if (t == 1023) row_ptr[N] = E;
}

// scatter edges into CSR order as packed {col, val_bits}
__global__ void fill_k(const int* __restrict__ row, const int* __restrict__ col,
                       const float* __restrict__ val, int* __restrict__ cursor,
                       int2* __restrict__ epack, int E){
    int e = blockIdx.x * blockDim.x + threadIdx.x;
    if (e >= E) return;
    int r = row[e];
    int pos = atomicAdd(&cursor[r], 1);
    int2 pk; pk.x = col[e]; pk.y = __float_as_int(val[e]);
    epack[pos] = pk;
}

// cur[n] = emb[idx[n]]; out[n] = b + a0 * (cur[n] @ W). One wave per node.
__global__ void gather_proj_k(const float* __restrict__ emb, const int* __restrict__ idx,
                              float* __restrict__ cur, const float* __restrict__ W,
                              const float* __restrict__ b, const float* __restrict__ a,
                              float* __restrict__ out, int N){
    int t = blockIdx.x * blockDim.x + threadIdx.x;
    int n = t >> 6;
    if (n >= N) return;
    int lane = t & 63;
    float2 x = ((const float2*)(emb + (size_t)idx[n] * 128))[lane];
    ((float2*)(cur + (size_t)n * 128))[lane] = x;
    int d0 = 2 * lane, d1 = d0 + 1;
    float s0 = x.x * W[d0 * 2]     + x.y * W[d1 * 2];
    float s1 = x.x * W[d0 * 2 + 1] + x.y * W[d1 * 2 + 1];
    for (int off = 32; off; off >>= 1){
        s0 += __shfl_down(s0, off);
        s1 += __shfl_down(s1, off);
    }
    if (lane == 0){
        float c = a[0];
        out[(size_t)n * 2]     = b[0] + c * s0;
        out[(size_t)n * 2 + 1] = b[1] + c * s1;
    }
}

// pull SpMM + fused projection: one wave per node, float2 per lane
__global__ void pull_k(const int* __restrict__ row_ptr, const int2* __restrict__ epack,
                       const float* __restrict__ cur, float* __restrict__ nxt,
                       const float* __restrict__ W, const float* __restrict__ a,
                       int ai, float* __restrict__ out, int N, int store){
    int t = blockIdx.x * blockDim.x + threadIdx.x;
    int n = t >> 6;
    if (n >= N) return;
    int lane = t & 63;
    int s = row_ptr[n], e = row_ptr[n + 1];
    float2 acc = make_float2(0.f, 0.f);
    for (int k = s; k < e; ++k){
        int2 p = epack[k];
        float v = __int_as_float(p.y);
        float2 m = ((const float2*)(cur + (size_t)p.x * 128))[lane];
        acc.x += v * m.x;
        acc.y += v * m.y;
    }
    if (store) ((float2*)(nxt + (size_t)n * 128))[lane] = acc;
    int d0 = 2 * lane, d1 = d0 + 1;
    float s0 = acc.x * W[d0 * 2]     + acc.y * W[d1 * 2];
    float s1 = acc.x * W[d0 * 2 + 1] + acc.y * W[d1 * 2 + 1];
    for (int off = 32; off; off >>= 1){
        s0 += __shfl_down(s0, off);
        s1 += __shfl_down(s1, off);
    }
    if (lane == 0){
        float c = a[ai];
        out[(size_t)n * 2]     += c * s0;
        out[(size_t)n * 2 + 1] += c * s1;
    }
}

extern "C" void kernel_launch(void* const* d_in, const int* in_sizes, int n_in,
                              void* d_out, int out_size, void* d_ws, size_t ws_size,
                              hipStream_t stream) {
    const int*   node_idx = (const int*)  d_in[0];
    const int*   adj_row  = (const int*)  d_in[1];
    const int*   adj_col  = (const int*)  d_in[2];
    const float* adj_val  = (const float*)d_in[3];
    const float* emb      = (const float*)d_in[4];
    const float* alpha    = (const float*)d_in[5];
    const float* W        = (const float*)d_in[6];
    const float* b        = (const float*)d_in[7];
    float* out = (float*)d_out;

    const int N = in_sizes[0];      // 100000
    const int E = in_sizes[1];      // 1600000
    const int L = in_sizes[5] - 1;  // 3
    const int D = 128;

    // workspace layout
    float* cur    = (float*)d_ws;                       // N*D
    float* nxt    = cur + (size_t)N * D;                // N*D
    int2*  epack  = (int2*)(nxt + (size_t)N * D);       // E int2
    int*   row_ptr= (int*)(epack + E);                  // N+1
    int*   cursor = row_ptr + (N + 1);                  // N
    int*   deg    = cursor + N;                         // N
    float* a      = (float*)(deg + N);                  // L+1

    softmax_k<<<1, 64, 0, stream>>>(alpha, a, L + 1);

    // CSR build
    zero_i<<<GD(N, 256), 256, 0, stream>>>(deg, N);
    hist_k<<<GD(E, 256), 256, 0, stream>>>(adj_row, deg, E);
    scan_k<<<1, 1024, 0, stream>>>(deg, row_ptr, cursor, N, E);
    fill_k<<<GD(E, 256), 256, 0, stream>>>(adj_row, adj_col, adj_val, cursor, epack, E);

    // layer 0: gather + proj
    gather_proj_k<<<GD(N * 64, 256), 256, 0, stream>>>(emb, node_idx, cur, W, b, a, out, N);

    // propagation layers, fused projection
    for (int i = 0; i < L; ++i){
        int store = (i < L - 1) ? 1 : 0;
        pull_k<<<GD(N * 64, 256), 256, 0, stream>>>(row_ptr, epack, cur, nxt, W, a,
                                                    i + 1, out, N, store);
        float* tmp = cur; cur = nxt; nxt = tmp;
    }
}

// Round 3
// 561.715 us; speedup vs baseline: 7.1272x; 1.7023x over previous
//
#include <hip/hip_runtime.h>

#define GD(x,y) (((x)+(y)-1)/(y))

// ---- softmax over alpha (tiny) ----
__global__ void softmax_k(const float* __restrict__ alpha, float* __restrict__ a, int n){
    if (threadIdx.x == 0 && blockIdx.x == 0){
        float m = alpha[0];
        for (int i = 1; i < n; ++i) m = fmaxf(m, alpha[i]);
        float s = 0.f;
        for (int i = 0; i < n; ++i){ float e = expf(alpha[i] - m); a[i] = e; s += e; }
        float inv = 1.f / s;
        for (int i = 0; i < n; ++i) a[i] *= inv;
    }
}

__global__ void zero_i(int* __restrict__ p, int n){
    int i = blockIdx.x * blockDim.x + threadIdx.x;
    if (i < n) p[i] = 0;
}

__global__ void hist_k(const int* __restrict__ row, int* __restrict__ deg, int E){
    int e = blockIdx.x * blockDim.x + threadIdx.x;
    if (e < E) atomicAdd(&deg[row[e]], 1);
}

// ---- hierarchical scan: 1024 elems per block ----
__global__ void scan1_k(const int* __restrict__ deg, int* __restrict__ bsum, int N){
    __shared__ int lds[256];
    int t = threadIdx.x;
    int base = blockIdx.x * 1024 + t * 4;
    int s = 0;
    #pragma unroll
    for (int j = 0; j < 4; ++j) if (base + j < N) s += deg[base + j];
    lds[t] = s; __syncthreads();
    for (int off = 128; off; off >>= 1){
        if (t < off) lds[t] += lds[t + off];
        __syncthreads();
    }
    if (t == 0) bsum[blockIdx.x] = lds[0];
}

// exclusive scan of up to 1024 block sums, in place
__global__ void scan2_k(int* __restrict__ bsum, int NB){
    __shared__ int lds[1024];
    int t = threadIdx.x;
    int v = (t < NB) ? bsum[t] : 0;
    lds[t] = v; __syncthreads();
    for (int off = 1; off < 1024; off <<= 1){
        int add = (t >= off) ? lds[t - off] : 0;
        __syncthreads();
        lds[t] += add;
        __syncthreads();
    }
    if (t < NB) bsum[t] = lds[t] - v;
}

__global__ void scan3_k(const int* __restrict__ deg, const int* __restrict__ bsum,
                        int* __restrict__ row_ptr, int* __restrict__ cursor, int N, int E){
    __shared__ int lds[256];
    int t = threadIdx.x;
    int base = blockIdx.x * 1024 + t * 4;
    int d[4]; int s = 0;
    #pragma unroll
    for (int j = 0; j < 4; ++j){ d[j] = (base + j < N) ? deg[base + j] : 0; s += d[j]; }
    lds[t] = s; __syncthreads();
    for (int off = 1; off < 256; off <<= 1){
        int add = (t >= off) ? lds[t - off] : 0;
        __syncthreads();
        lds[t] += add;
        __syncthreads();
    }
    int run = bsum[blockIdx.x] + lds[t] - s;
    #pragma unroll
    for (int j = 0; j < 4; ++j){
        int i = base + j;
        if (i < N){ row_ptr[i] = run; cursor[i] = run; run += d[j]; }
    }
    if (blockIdx.x == 0 && t == 0) row_ptr[N] = E;
}

// scatter edges into CSR order as packed {col, val_bits}
__global__ void fill_k(const int* __restrict__ row, const int* __restrict__ col,
                       const float* __restrict__ val, int* __restrict__ cursor,
                       int2* __restrict__ epack, int E){
    int e = blockIdx.x * blockDim.x + threadIdx.x;
    if (e >= E) return;
    int r = row[e];
    int pos = atomicAdd(&cursor[r], 1);
    int2 pk; pk.x = col[e]; pk.y = __float_as_int(val[e]);
    epack[pos] = pk;
}

// cur[n] = emb[idx[n]]; out[n] = b + a0 * (cur[n] @ W). One wave per node.
__global__ void gather_proj_k(const float* __restrict__ emb, const int* __restrict__ idx,
                              float* __restrict__ cur, const float* __restrict__ W,
                              const float* __restrict__ b, const float* __restrict__ a,
                              float* __restrict__ out, int N){
    int t = blockIdx.x * blockDim.x + threadIdx.x;
    int n = t >> 6;
    if (n >= N) return;
    int lane = t & 63;
    float2 x = ((const float2*)(emb + (size_t)idx[n] * 128))[lane];
    ((float2*)(cur + (size_t)n * 128))[lane] = x;
    int d0 = 2 * lane, d1 = d0 + 1;
    float s0 = x.x * W[d0 * 2]     + x.y * W[d1 * 2];
    float s1 = x.x * W[d0 * 2 + 1] + x.y * W[d1 * 2 + 1];
    for (int off = 32; off; off >>= 1){
        s0 += __shfl_down(s0, off);
        s1 += __shfl_down(s1, off);
    }
    if (lane == 0){
        float c = a[0];
        out[(size_t)n * 2]     = b[0] + c * s0;
        out[(size_t)n * 2 + 1] = b[1] + c * s1;
    }
}

// pull SpMM + fused projection: one wave per node, float2 per lane, 4-edge batches
__global__ void pull_k(const int* __restrict__ row_ptr, const int2* __restrict__ epack,
                       const float* __restrict__ cur, float* __restrict__ nxt,
                       const float* __restrict__ W, const float* __restrict__ a,
                       int ai, float* __restrict__ out, int N, int store){
    int t = blockIdx.x * blockDim.x + threadIdx.x;
    int n = t >> 6;
    if (n >= N) return;
    int lane = t & 63;
    int s = row_ptr[n], e = row_ptr[n + 1];
    float2 acc = make_float2(0.f, 0.f);
    int k = s;
    for (; k + 4 <= e; k += 4){
        int2 p0 = epack[k], p1 = epack[k+1], p2 = epack[k+2], p3 = epack[k+3];
        float2 m0 = ((const float2*)(cur + (size_t)p0.x * 128))[lane];
        float2 m1 = ((const float2*)(cur + (size_t)p1.x * 128))[lane];
        float2 m2 = ((const float2*)(cur + (size_t)p2.x * 128))[lane];
        float2 m3 = ((const float2*)(cur + (size_t)p3.x * 128))[lane];
        float v0 = __int_as_float(p0.y), v1 = __int_as_float(p1.y);
        float v2 = __int_as_float(p2.y), v3 = __int_as_float(p3.y);
        acc.x += v0 * m0.x + v1 * m1.x + v2 * m2.x + v3 * m3.x;
        acc.y += v0 * m0.y + v1 * m1.y + v2 * m2.y + v3 * m3.y;
    }
    for (; k < e; ++k){
        int2 p = epack[k];
        float v = __int_as_float(p.y);
        float2 m = ((const float2*)(cur + (size_t)p.x * 128))[lane];
        acc.x += v * m.x;
        acc.y += v * m.y;
    }
    if (store) ((float2*)(nxt + (size_t)n * 128))[lane] = acc;
    int d0 = 2 * lane, d1 = d0 + 1;
    float s0 = acc.x * W[d0 * 2]     + acc.y * W[d1 * 2];
    float s1 = acc.x * W[d0 * 2 + 1] + acc.y * W[d1 * 2 + 1];
    for (int off = 32; off; off >>= 1){
        s0 += __shfl_down(s0, off);
        s1 += __shfl_down(s1, off);
    }
    if (lane == 0){
        float c = a[ai];
        out[(size_t)n * 2]     += c * s0;
        out[(size_t)n * 2 + 1] += c * s1;
    }
}

extern "C" void kernel_launch(void* const* d_in, const int* in_sizes, int n_in,
                              void* d_out, int out_size, void* d_ws, size_t ws_size,
                              hipStream_t stream) {
    const int*   node_idx = (const int*)  d_in[0];
    const int*   adj_row  = (const int*)  d_in[1];
    const int*   adj_col  = (const int*)  d_in[2];
    const float* adj_val  = (const float*)d_in[3];
    const float* emb      = (const float*)d_in[4];
    const float* alpha    = (const float*)d_in[5];
    const float* W        = (const float*)d_in[6];
    const float* b        = (const float*)d_in[7];
    float* out = (float*)d_out;

    const int N = in_sizes[0];      // 100000
    const int E = in_sizes[1];      // 1600000
    const int L = in_sizes[5] - 1;  // 3
    const int D = 128;
    const int NB = GD(N, 1024);     // scan blocks (must be <= 1024)

    // workspace layout (16B-aligned chunks)
    char* w = (char*)d_ws;
    float* cur    = (float*)w;                 w += (size_t)N * D * 4;
    float* nxt    = (float*)w;                 w += (size_t)N * D * 4;
    int2*  epack  = (int2*)w;                  w += (size_t)E * 8;
    int*   row_ptr= (int*)w;                   w += ((size_t)N + 4) * 4;
    int*   cursor = (int*)w;                   w += (size_t)N * 4;
    int*   deg    = (int*)w;                   w += (size_t)N * 4;
    int*   bsum   = (int*)w;                   w += 4096;
    float* a      = (float*)w;

    softmax_k<<<1, 64, 0, stream>>>(alpha, a, L + 1);

    // CSR build
    zero_i<<<GD(N, 256), 256, 0, stream>>>(deg, N);
    hist_k<<<GD(E, 256), 256, 0, stream>>>(adj_row, deg, E);
    scan1_k<<<NB, 256, 0, stream>>>(deg, bsum, N);
    scan2_k<<<1, 1024, 0, stream>>>(bsum, NB);
    scan3_k<<<NB, 256, 0, stream>>>(deg, bsum, row_ptr, cursor, N, E);
    fill_k<<<GD(E, 256), 256, 0, stream>>>(adj_row, adj_col, adj_val, cursor, epack, E);

    // layer 0: gather + proj
    gather_proj_k<<<GD(N * 64, 256), 256, 0, stream>>>(emb, node_idx, cur, W, b, a, out, N);

    // propagation layers, fused projection
    for (int i = 0; i < L; ++i){
        int store = (i < L - 1) ? 1 : 0;
        pull_k<<<GD(N * 64, 256), 256, 0, stream>>>(row_ptr, epack, cur, nxt, W, a,
                                                    i + 1, out, N, store);
        float* tmp = cur; cur = nxt; nxt = tmp;
    }
}

// Round 4
// 524.748 us; speedup vs baseline: 7.6293x; 1.0704x over previous
//
#include <hip/hip_runtime.h>

#define GD(x,y) (((x)+(y)-1)/(y))

// ---- softmax over alpha (tiny) ----
__global__ void softmax_k(const float* __restrict__ alpha, float* __restrict__ a, int n){
    if (threadIdx.x == 0 && blockIdx.x == 0){
        float m = alpha[0];
        for (int i = 1; i < n; ++i) m = fmaxf(m, alpha[i]);
        float s = 0.f;
        for (int i = 0; i < n; ++i){ float e = expf(alpha[i] - m); a[i] = e; s += e; }
        float inv = 1.f / s;
        for (int i = 0; i < n; ++i) a[i] *= inv;
    }
}

// y[n] = emb[idx[n]] @ W  (128 -> 2); nxt[n] = 0; out[n] = b + a0 * y[n].
// One wave per node; lane handles dims {2*lane, 2*lane+1}.
__global__ void proj_k(const float* __restrict__ emb, const int* __restrict__ idx,
                       const float* __restrict__ W, const float* __restrict__ b,
                       const float* __restrict__ a, float* __restrict__ y,
                       float* __restrict__ nxt, float* __restrict__ out, int N){
    int t = blockIdx.x * blockDim.x + threadIdx.x;
    int n = t >> 6;
    if (n >= N) return;
    int lane = t & 63;
    float2 x = ((const float2*)(emb + (size_t)idx[n] * 128))[lane];
    int d0 = 2 * lane;
    float s0 = x.x * W[d0 * 2]     + x.y * W[d0 * 2 + 2];
    float s1 = x.x * W[d0 * 2 + 1] + x.y * W[d0 * 2 + 3];
    for (int off = 32; off; off >>= 1){
        s0 += __shfl_down(s0, off);
        s1 += __shfl_down(s1, off);
    }
    if (lane == 0){
        float c = a[0];
        ((float2*)y)[n]   = make_float2(s0, s1);
        ((float2*)nxt)[n] = make_float2(0.f, 0.f);
        ((float2*)out)[n] = make_float2(b[0] + c * s0, b[1] + c * s1);
    }
}

// push SpMM at D=2: one thread per edge, 2 fp32 atomics into nxt[row]
__global__ void spmm2_k(const int* __restrict__ row, const int* __restrict__ col,
                        const float* __restrict__ val, const float* __restrict__ y,
                        float* __restrict__ nxt, int E){
    int e = blockIdx.x * blockDim.x + threadIdx.x;
    if (e >= E) return;
    int r = row[e], c = col[e];
    float v = val[e];
    float2 m = ((const float2*)y)[c];
    atomicAdd(&nxt[2 * (size_t)r],     v * m.x);
    atomicAdd(&nxt[2 * (size_t)r + 1], v * m.y);
}

// out[n] += a[ai] * nxt[n]; zero the old cur buffer (next scatter target)
__global__ void fuse_k(const float* __restrict__ nxt, float* __restrict__ cur_zero,
                       const float* __restrict__ a, int ai, float* __restrict__ out, int N){
    int n = blockIdx.x * blockDim.x + threadIdx.x;
    if (n >= N) return;
    float c = a[ai];
    float2 z = ((const float2*)nxt)[n];
    float2 o = ((float2*)out)[n];
    o.x += c * z.x; o.y += c * z.y;
    ((float2*)out)[n] = o;
    ((float2*)cur_zero)[n] = make_float2(0.f, 0.f);
}

extern "C" void kernel_launch(void* const* d_in, const int* in_sizes, int n_in,
                              void* d_out, int out_size, void* d_ws, size_t ws_size,
                              hipStream_t stream) {
    const int*   node_idx = (const int*)  d_in[0];
    const int*   adj_row  = (const int*)  d_in[1];
    const int*   adj_col  = (const int*)  d_in[2];
    const float* adj_val  = (const float*)d_in[3];
    const float* emb      = (const float*)d_in[4];
    const float* alpha    = (const float*)d_in[5];
    const float* W        = (const float*)d_in[6];
    const float* b        = (const float*)d_in[7];
    float* out = (float*)d_out;

    const int N = in_sizes[0];      // 100000
    const int E = in_sizes[1];      // 1600000
    const int L = in_sizes[5] - 1;  // 3

    // workspace: two [N,2] fp32 buffers + softmax(alpha)
    float* cur = (float*)d_ws;                  // N*2
    float* nxt = cur + (size_t)N * 2;           // N*2
    float* a   = nxt + (size_t)N * 2;           // L+1

    softmax_k<<<1, 64, 0, stream>>>(alpha, a, L + 1);

    // layer 0: project to 2 dims, init out, zero scatter target
    proj_k<<<GD(N * 64, 256), 256, 0, stream>>>(emb, node_idx, W, b, a, cur, nxt, out, N);

    for (int i = 0; i < L; ++i){
        spmm2_k<<<GD(E, 256), 256, 0, stream>>>(adj_row, adj_col, adj_val, cur, nxt, E);
        // out += a[i+1]*nxt; zero old cur so it can be the next scatter target
        fuse_k<<<GD(N, 256), 256, 0, stream>>>(nxt, cur, a, i + 1, out, N);
        float* tmp = cur; cur = nxt; nxt = tmp;
    }
}

// Round 5
// 141.681 us; speedup vs baseline: 28.2570x; 3.7037x over previous
//
#include <hip/hip_runtime.h>

#define GD(x,y) (((x)+(y)-1)/(y))

#define SH   7                 // rows per bucket = 128
#define BPR  (1 << SH)
#define G1   256               // blocks in hist/fill passes
#define BS   256

// ---- softmax over alpha (tiny) ----
__global__ void softmax_k(const float* __restrict__ alpha, float* __restrict__ a, int n){
    if (threadIdx.x == 0 && blockIdx.x == 0){
        float m = alpha[0];
        for (int i = 1; i < n; ++i) m = fmaxf(m, alpha[i]);
        float s = 0.f;
        for (int i = 0; i < n; ++i){ float e = expf(alpha[i] - m); a[i] = e; s += e; }
        float inv = 1.f / s;
        for (int i = 0; i < n; ++i) a[i] *= inv;
    }
}

// P1: per-block bucket histogram (LDS), cnt layout bucket-major: cnt[b*G1 + blk]
__global__ void histb_k(const int* __restrict__ row, int* __restrict__ cnt,
                        int E, int NBK, int chunk){
    __shared__ int h[1024];            // NBK <= 1024 (N <= 131072)
    for (int i = threadIdx.x; i < NBK; i += BS) h[i] = 0;
    __syncthreads();
    int s = blockIdx.x * chunk, e = min(E, s + chunk);
    for (int i = s + threadIdx.x; i < e; i += BS)
        atomicAdd(&h[row[i] >> SH], 1);
    __syncthreads();
    for (int i = threadIdx.x; i < NBK; i += BS)
        cnt[i * G1 + blockIdx.x] = h[i];
}

// ---- generic hierarchical exclusive scan over M ints (M <= 1024*1024) ----
__global__ void scanA_k(const int* __restrict__ in, int* __restrict__ bsum, int M){
    __shared__ int lds[256];
    int t = threadIdx.x;
    int base = blockIdx.x * 1024 + t * 4;
    int s = 0;
    #pragma unroll
    for (int j = 0; j < 4; ++j) if (base + j < M) s += in[base + j];
    lds[t] = s; __syncthreads();
    for (int off = 128; off; off >>= 1){
        if (t < off) lds[t] += lds[t + off];
        __syncthreads();
    }
    if (t == 0) bsum[blockIdx.x] = lds[0];
}

__global__ void scanB_k(int* __restrict__ bsum, int NB){
    __shared__ int lds[1024];
    int t = threadIdx.x;
    int v = (t < NB) ? bsum[t] : 0;
    lds[t] = v; __syncthreads();
    for (int off = 1; off < 1024; off <<= 1){
        int add = (t >= off) ? lds[t - off] : 0;
        __syncthreads();
        lds[t] += add;
        __syncthreads();
    }
    if (t < NB) bsum[t] = lds[t] - v;
}

__global__ void scanC_k(const int* __restrict__ in, const int* __restrict__ bsum,
                        int* __restrict__ outx, int M){
    __shared__ int lds[256];
    int t = threadIdx.x;
    int base = blockIdx.x * 1024 + t * 4;
    int d[4]; int s = 0;
    #pragma unroll
    for (int j = 0; j < 4; ++j){ d[j] = (base + j < M) ? in[base + j] : 0; s += d[j]; }
    lds[t] = s; __syncthreads();
    for (int off = 1; off < 256; off <<= 1){
        int add = (t >= off) ? lds[t - off] : 0;
        __syncthreads();
        lds[t] += add;
        __syncthreads();
    }
    int run = bsum[blockIdx.x] + lds[t] - s;
    #pragma unroll
    for (int j = 0; j < 4; ++j){
        int i = base + j;
        if (i < M){ outx[i] = run; run += d[j]; }
    }
}

// bucket boundaries: bptr[b] = base[b*G1], bptr[NBK] = E
__global__ void bptr_k(const int* __restrict__ base, int* __restrict__ bptr, int NBK, int E){
    int b = blockIdx.x * blockDim.x + threadIdx.x;
    if (b < NBK) bptr[b] = base[b * G1];
    if (b == NBK) bptr[b] = E;
}

// P3: scatter edges into bucket order via LDS cursors; pack {col | rloc<<17, val}
__global__ void fill3_k(const int* __restrict__ row, const int* __restrict__ col,
                        const float* __restrict__ val, const int* __restrict__ base,
                        int2* __restrict__ sep, int E, int NBK, int chunk){
    __shared__ int cur[1024];
    for (int i = threadIdx.x; i < NBK; i += BS)
        cur[i] = base[i * G1 + blockIdx.x];
    __syncthreads();
    int s = blockIdx.x * chunk, e = min(E, s + chunk);
    for (int i = s + threadIdx.x; i < e; i += BS){
        int r = row[i];
        int b = r >> SH;
        int pos = atomicAdd(&cur[b], 1);
        int2 pk;
        pk.x = col[i] | ((r & (BPR - 1)) << 17);
        pk.y = __float_as_int(val[i]);
        sep[pos] = pk;
    }
}

// y[n] = emb[idx[n]] @ W (128->2); out[n] = b + a0*y[n]. One wave per node.
__global__ void proj_k(const float* __restrict__ emb, const int* __restrict__ idx,
                       const float* __restrict__ W, const float* __restrict__ b,
                       const float* __restrict__ a, float* __restrict__ y,
                       float* __restrict__ out, int N){
    int t = blockIdx.x * blockDim.x + threadIdx.x;
    int n = t >> 6;
    if (n >= N) return;
    int lane = t & 63;
    float2 x = ((const float2*)(emb + (size_t)idx[n] * 128))[lane];
    int d0 = 2 * lane;
    float s0 = x.x * W[d0 * 2]     + x.y * W[d0 * 2 + 2];
    float s1 = x.x * W[d0 * 2 + 1] + x.y * W[d0 * 2 + 3];
    for (int off = 32; off; off >>= 1){
        s0 += __shfl_down(s0, off);
        s1 += __shfl_down(s1, off);
    }
    if (lane == 0){
        float c = a[0];
        ((float2*)y)[n]   = make_float2(s0, s1);
        ((float2*)out)[n] = make_float2(b[0] + c * s0, b[1] + c * s1);
    }
}

// bucketed push SpMM: one block per bucket, LDS accumulator, no global atomics.
// nxt[rows of bucket] = segment_sum; out += a[ai]*nxt (bucket owns its rows).
__global__ void spmmb_k(const int* __restrict__ bptr, const int2* __restrict__ sep,
                        const float* __restrict__ y, float* __restrict__ nxt,
                        const float* __restrict__ a, int ai,
                        float* __restrict__ out, int N){
    __shared__ float acc[BPR * 2];     // 256 floats
    int b = blockIdx.x;
    int t = threadIdx.x;
    acc[t] = 0.f;
    __syncthreads();
    int s = bptr[b], e = bptr[b + 1];
    for (int i = s + t; i < e; i += BS){
        int2 pk = sep[i];
        int c  = pk.x & 0x1FFFF;
        int rl = pk.x >> 17;
        float v = __int_as_float(pk.y);
        float2 m = ((const float2*)y)[c];
        atomicAdd(&acc[2 * rl],     v * m.x);
        atomicAdd(&acc[2 * rl + 1], v * m.y);
    }
    __syncthreads();
    int n = (b << SH) + (t >> 1);
    if (n < N){
        size_t gi = ((size_t)(b << SH)) * 2 + t;
        float z = acc[t];
        nxt[gi] = z;
        out[gi] += a[ai] * z;
    }
}

extern "C" void kernel_launch(void* const* d_in, const int* in_sizes, int n_in,
                              void* d_out, int out_size, void* d_ws, size_t ws_size,
                              hipStream_t stream) {
    const int*   node_idx = (const int*)  d_in[0];
    const int*   adj_row  = (const int*)  d_in[1];
    const int*   adj_col  = (const int*)  d_in[2];
    const float* adj_val  = (const float*)d_in[3];
    const float* emb      = (const float*)d_in[4];
    const float* alpha    = (const float*)d_in[5];
    const float* W        = (const float*)d_in[6];
    const float* b        = (const float*)d_in[7];
    float* out = (float*)d_out;

    const int N = in_sizes[0];      // 100000
    const int E = in_sizes[1];      // 1600000
    const int L = in_sizes[5] - 1;  // 3
    const int NBK = GD(N, BPR);     // 782 buckets (<= 1024)
    const int M = NBK * G1;         // flattened (bucket,block) counts
    const int NBA = GD(M, 1024);    // scan blocks for M (<= 1024)
    const int chunk = GD(E, G1);

    // workspace
    char* w = (char*)d_ws;
    float* y    = (float*)w;  w += (size_t)N * 2 * 4;
    float* nxt  = (float*)w;  w += (size_t)N * 2 * 4;
    int2*  sep  = (int2*)w;   w += (size_t)E * 8;
    int*   cnt  = (int*)w;    w += (size_t)M * 4;
    int*   bas  = (int*)w;    w += (size_t)M * 4;
    int*   bsum = (int*)w;    w += 4096;
    int*   bptr = (int*)w;    w += ((size_t)NBK + 2) * 4;
    float* a    = (float*)w;

    softmax_k<<<1, 64, 0, stream>>>(alpha, a, L + 1);

    // one-time bucket counting sort of edges (no global atomics)
    histb_k<<<G1, BS, 0, stream>>>(adj_row, cnt, E, NBK, chunk);
    scanA_k<<<NBA, 256, 0, stream>>>(cnt, bsum, M);
    scanB_k<<<1, 1024, 0, stream>>>(bsum, NBA);
    scanC_k<<<NBA, 256, 0, stream>>>(cnt, bsum, bas, M);
    bptr_k<<<GD(NBK + 1, 256), 256, 0, stream>>>(bas, bptr, NBK, E);
    fill3_k<<<G1, BS, 0, stream>>>(adj_row, adj_col, adj_val, bas, sep, E, NBK, chunk);

    // layer 0: project to 2 dims, init out
    proj_k<<<GD(N * 64, 256), 256, 0, stream>>>(emb, node_idx, W, b, a, y, out, N);

    // propagation layers: bucketed SpMM with fused out-accumulation
    for (int i = 0; i < L; ++i){
        spmmb_k<<<NBK, BS, 0, stream>>>(bptr, sep, y, nxt, a, i + 1, out, N);
        float* tmp = y; y = nxt; nxt = tmp;
    }
}

// Round 6
// 136.735 us; speedup vs baseline: 29.2791x; 1.0362x over previous
//
#include <hip/hip_runtime.h>

#define GD(x,y) (((x)+(y)-1)/(y))

#define SH   7                 // rows per bucket = 128
#define BPR  (1 << SH)
#define G1   1024              // blocks in hist/fill passes
#define BS   256

// P1: per-block bucket histogram (LDS), cnt layout bucket-major: cnt[b*G1 + blk]
__global__ void histb_k(const int* __restrict__ row, int* __restrict__ cnt,
                        int E, int NBK, int chunk){
    __shared__ int h[1024];            // NBK <= 1024 (N <= 131072)
    for (int i = threadIdx.x; i < NBK; i += BS) h[i] = 0;
    __syncthreads();
    int s = blockIdx.x * chunk, e = min(E, s + chunk);
    for (int i = s + threadIdx.x; i < e; i += BS)
        atomicAdd(&h[row[i] >> SH], 1);
    __syncthreads();
    for (int i = threadIdx.x; i < NBK; i += BS)
        cnt[(size_t)i * G1 + blockIdx.x] = h[i];
}

// ---- hierarchical exclusive scan over M ints ----
__global__ void scanA_k(const int* __restrict__ in, int* __restrict__ bsum, int M){
    __shared__ int lds[256];
    int t = threadIdx.x;
    int base = blockIdx.x * 1024 + t * 4;
    int s = 0;
    #pragma unroll
    for (int j = 0; j < 4; ++j) if (base + j < M) s += in[base + j];
    lds[t] = s; __syncthreads();
    for (int off = 128; off; off >>= 1){
        if (t < off) lds[t] += lds[t + off];
        __syncthreads();
    }
    if (t == 0) bsum[blockIdx.x] = lds[0];
}

// scanB + softmax(alpha) fused (both single-block-scale work)
__global__ void scanB_k(int* __restrict__ bsum, int NB,
                        const float* __restrict__ alpha, float* __restrict__ a, int na){
    __shared__ int lds[1024];
    int t = threadIdx.x;
    if (t == 0){
        float m = alpha[0];
        for (int i = 1; i < na; ++i) m = fmaxf(m, alpha[i]);
        float s = 0.f;
        for (int i = 0; i < na; ++i){ float e = expf(alpha[i] - m); a[i] = e; s += e; }
        float inv = 1.f / s;
        for (int i = 0; i < na; ++i) a[i] *= inv;
    }
    int v = (t < NB) ? bsum[t] : 0;
    lds[t] = v; __syncthreads();
    for (int off = 1; off < 1024; off <<= 1){
        int add = (t >= off) ? lds[t - off] : 0;
        __syncthreads();
        lds[t] += add;
        __syncthreads();
    }
    if (t < NB) bsum[t] = lds[t] - v;
}

__global__ void scanC_k(const int* __restrict__ in, const int* __restrict__ bsum,
                        int* __restrict__ outx, int M){
    __shared__ int lds[256];
    int t = threadIdx.x;
    int base = blockIdx.x * 1024 + t * 4;
    int d[4]; int s = 0;
    #pragma unroll
    for (int j = 0; j < 4; ++j){ d[j] = (base + j < M) ? in[base + j] : 0; s += d[j]; }
    lds[t] = s; __syncthreads();
    for (int off = 1; off < 256; off <<= 1){
        int add = (t >= off) ? lds[t - off] : 0;
        __syncthreads();
        lds[t] += add;
        __syncthreads();
    }
    int run = bsum[blockIdx.x] + lds[t] - s;
    #pragma unroll
    for (int j = 0; j < 4; ++j){
        int i = base + j;
        if (i < M){ outx[i] = run; run += d[j]; }
    }
}

// P3: scatter edges into bucket order via LDS cursors; pack {col | rloc<<17, val}
__global__ void fill3_k(const int* __restrict__ row, const int* __restrict__ col,
                        const float* __restrict__ val, const int* __restrict__ base,
                        int2* __restrict__ sep, int E, int NBK, int chunk){
    __shared__ int cur[1024];
    for (int i = threadIdx.x; i < NBK; i += BS)
        cur[i] = base[(size_t)i * G1 + blockIdx.x];
    __syncthreads();
    int s = blockIdx.x * chunk, e = min(E, s + chunk);
    for (int i = s + threadIdx.x; i < e; i += BS){
        int r = row[i];
        int b = r >> SH;
        int pos = atomicAdd(&cur[b], 1);
        int2 pk;
        pk.x = col[i] | ((r & (BPR - 1)) << 17);
        pk.y = __float_as_int(val[i]);
        sep[pos] = pk;
    }
}

// y[n] = emb[idx[n]] @ W (128->2); out[n] = b + a0*y[n].
// Two rows per wave: lane = (row-half)*32 + sl, float4 per lane.
__global__ void proj_k(const float* __restrict__ emb, const int* __restrict__ idx,
                       const float* __restrict__ W, const float* __restrict__ b,
                       const float* __restrict__ a, float* __restrict__ y,
                       float* __restrict__ out, int N){
    int t = blockIdx.x * blockDim.x + threadIdx.x;
    int w = t >> 6;
    int lane = t & 63;
    int n = w * 2 + (lane >> 5);
    if (n >= N) return;
    int sl = lane & 31;
    float4 x = ((const float4*)(emb + (size_t)idx[n] * 128))[sl];
    int d0 = 4 * sl;
    float s0 = x.x * W[d0*2]   + x.y * W[d0*2+2] + x.z * W[d0*2+4] + x.w * W[d0*2+6];
    float s1 = x.x * W[d0*2+1] + x.y * W[d0*2+3] + x.z * W[d0*2+5] + x.w * W[d0*2+7];
    #pragma unroll
    for (int off = 16; off; off >>= 1){
        s0 += __shfl_down(s0, off, 32);
        s1 += __shfl_down(s1, off, 32);
    }
    if (sl == 0){
        float c = a[0];
        ((float2*)y)[n]   = make_float2(s0, s1);
        ((float2*)out)[n] = make_float2(b[0] + c * s0, b[1] + c * s1);
    }
}

// bucketed push SpMM: one block per bucket, plane-split LDS accumulator.
__global__ void spmmb_k(const int* __restrict__ bas, const int2* __restrict__ sep,
                        const float* __restrict__ y, float* __restrict__ nxt,
                        const float* __restrict__ a, int ai,
                        float* __restrict__ out, int N, int NBK, int E){
    __shared__ float accx[BPR];
    __shared__ float accy[BPR];
    int b = blockIdx.x;
    int t = threadIdx.x;
    if (t < BPR){ accx[t] = 0.f; accy[t] = 0.f; }
    __syncthreads();
    int s = bas[(size_t)b * G1];
    int e = (b + 1 < NBK) ? bas[(size_t)(b + 1) * G1] : E;
    for (int i = s + t; i < e; i += BS){
        int2 pk = sep[i];
        int c  = pk.x & 0x1FFFF;
        int rl = pk.x >> 17;
        float v = __int_as_float(pk.y);
        float2 m = ((const float2*)y)[c];
        atomicAdd(&accx[rl], v * m.x);
        atomicAdd(&accy[rl], v * m.y);
    }
    __syncthreads();
    if (t < BPR){
        int n = (b << SH) + t;
        if (n < N){
            float2 z = make_float2(accx[t], accy[t]);
            ((float2*)nxt)[n] = z;
            float2 o = ((float2*)out)[n];
            o.x += a[ai] * z.x; o.y += a[ai] * z.y;
            ((float2*)out)[n] = o;
        }
    }
}

extern "C" void kernel_launch(void* const* d_in, const int* in_sizes, int n_in,
                              void* d_out, int out_size, void* d_ws, size_t ws_size,
                              hipStream_t stream) {
    const int*   node_idx = (const int*)  d_in[0];
    const int*   adj_row  = (const int*)  d_in[1];
    const int*   adj_col  = (const int*)  d_in[2];
    const float* adj_val  = (const float*)d_in[3];
    const float* emb      = (const float*)d_in[4];
    const float* alpha    = (const float*)d_in[5];
    const float* W        = (const float*)d_in[6];
    const float* b        = (const float*)d_in[7];
    float* out = (float*)d_out;

    const int N = in_sizes[0];      // 100000
    const int E = in_sizes[1];      // 1600000
    const int L = in_sizes[5] - 1;  // 3
    const int NBK = GD(N, BPR);     // 782 buckets (<= 1024)
    const int M = NBK * G1;         // flattened (bucket,block) counts
    const int NBA = GD(M, 1024);    // scan blocks for M (<= 1024)
    const int chunk = GD(E, G1);

    // workspace
    char* w = (char*)d_ws;
    float* y    = (float*)w;  w += (size_t)N * 2 * 4;
    float* nxt  = (float*)w;  w += (size_t)N * 2 * 4;
    int2*  sep  = (int2*)w;   w += (size_t)E * 8;
    int*   cnt  = (int*)w;    w += (size_t)M * 4;
    int*   bas  = (int*)w;    w += (size_t)M * 4;
    int*   bsum = (int*)w;    w += 4096;
    float* a    = (float*)w;

    // one-time bucket counting sort of edges (no global atomics)
    histb_k<<<G1, BS, 0, stream>>>(adj_row, cnt, E, NBK, chunk);
    scanA_k<<<NBA, 256, 0, stream>>>(cnt, bsum, M);
    scanB_k<<<1, 1024, 0, stream>>>(bsum, NBA, alpha, a, L + 1);
    scanC_k<<<NBA, 256, 0, stream>>>(cnt, bsum, bas, M);
    fill3_k<<<G1, BS, 0, stream>>>(adj_row, adj_col, adj_val, bas, sep, E, NBK, chunk);

    // layer 0: project to 2 dims, init out
    proj_k<<<GD(N * 32, 256), 256, 0, stream>>>(emb, node_idx, W, b, a, y, out, N);

    // propagation layers: bucketed SpMM with fused out-accumulation
    for (int i = 0; i < L; ++i){
        spmmb_k<<<NBK, BS, 0, stream>>>(bas, sep, y, nxt, a, i + 1, out, N, NBK, E);
        float* tmp = y; y = nxt; nxt = tmp;
    }
}